// Round 1
// baseline (406.168 us; speedup 1.0000x reference)
//
#include <hip/hip_runtime.h>

// Problem constants
// B=16, H=256, W=256, CIN=COUT=32, modes: kh in {0..15, 240..255}, kw in 0..16
#define NB 16
#define NH 256
#define NW 256
#define NC 32
#define EM1 17
#define TWO_PI 6.283185307179586f

// ---------------- K1: forward W-DFT (256 -> 17 complex bins), x(1/65536) -------------
// grid = B*H blocks (one per (b,y) row), 256 threads
// Xw layout: [b][kw][y][i] float2 : idx = b*17*8192 + kw*8192 + y*32 + i
__global__ __launch_bounds__(256) void k1_fwdW(const float* __restrict__ x,
                                               float2* __restrict__ Xw) {
    __shared__ float xl[32 * 257];          // [i][x], stride 257 (conflict-free)
    __shared__ float redr[8 * 33];
    __shared__ float redi[8 * 33];
    int blk = blockIdx.x;                   // b*256 + y
    int b = blk >> 8, y = blk & 255;
    const float* row = x + (size_t)blk * (NW * NC);
    int t = threadIdx.x;
    // stage row: global [x][i] -> LDS [i][x]
    for (int c = 0; c < 32; ++c) {
        int g = (c << 8) + t;               // g = x*32 + i
        xl[(g & 31) * 257 + (g >> 5)] = row[g];
    }
    __syncthreads();

    int i = t & 31, g = t >> 5;             // g in 0..7 -> kw = g and g+8
    float s0, c0, s1, c1;
    sincosf(-TWO_PI * (float)g / 256.f, &s0, &c0);        // w0 = e^{-2pi i g/256}
    sincosf(-TWO_PI * (float)(g + 8) / 256.f, &s1, &c1);
    float t0r = 1.f, t0i = 0.f, t1r = 1.f, t1i = 0.f;
    float a0r = 0.f, a0i = 0.f, a1r = 0.f, a1i = 0.f;
    const float* xp = &xl[i * 257];
    for (int xx = 0; xx < 256; ++xx) {
        float xv = xp[xx];
        a0r = fmaf(xv, t0r, a0r); a0i = fmaf(xv, t0i, a0i);
        a1r = fmaf(xv, t1r, a1r); a1i = fmaf(xv, t1i, a1i);
        float n0r = t0r * c0 - t0i * s0, n0i = t0r * s0 + t0i * c0;
        t0r = n0r; t0i = n0i;
        float n1r = t1r * c1 - t1i * s1, n1i = t1r * s1 + t1i * c1;
        t1r = n1r; t1i = n1i;
    }
    // kw = 16 handled cooperatively: each thread does x-chunk [32g, 32g+32)
    // start twiddle e^{-2pi i*16*(32g)/256} = e^{-2pi i*2g} = 1 exactly
    float sw, cw;
    sincosf(-TWO_PI * 16.f / 256.f, &sw, &cw);
    float pr = 0.f, pim = 0.f, ur = 1.f, ui = 0.f;
    const int x0 = g * 32;
    for (int xx = x0; xx < x0 + 32; ++xx) {
        float xv = xp[xx];
        pr = fmaf(xv, ur, pr); pim = fmaf(xv, ui, pim);
        float nr = ur * cw - ui * sw, ni = ur * sw + ui * cw;
        ur = nr; ui = ni;
    }
    redr[g * 33 + i] = pr; redi[g * 33 + i] = pim;

    const float sc = 1.0f / 65536.0f;       // norm="forward": 1/(H*W)
    size_t base = (size_t)b * (17 * 8192) + (size_t)y * 32 + i;
    Xw[base + (size_t)g * 8192]       = make_float2(a0r * sc, a0i * sc);
    Xw[base + (size_t)(g + 8) * 8192] = make_float2(a1r * sc, a1i * sc);
    __syncthreads();
    if (t < 32) {
        float sr = 0.f, si = 0.f;
#pragma unroll
        for (int gg = 0; gg < 8; ++gg) { sr += redr[gg * 33 + t]; si += redi[gg * 33 + t]; }
        Xw[(size_t)b * (17 * 8192) + (size_t)16 * 8192 + (size_t)y * 32 + t] =
            make_float2(sr * sc, si * sc);
    }
}

// ---------------- K2: forward H-DFT at 32 kept kh rows -------------
// grid = B*17 blocks, 256 threads. xft layout: [b][m][kw][i] f2, m-stride 544, b-stride 17408
__global__ __launch_bounds__(256) void k2_fwdH(const float2* __restrict__ Xw,
                                               float2* __restrict__ xft) {
    __shared__ float xr[8192];              // [i][y] with rotate-swizzle, 32 KB
    __shared__ float xi[8192];
    int bk = blockIdx.x;                    // b*17 + kw
    int b = bk / 17, kw = bk - b * 17;
    const float2* src = Xw + (size_t)bk * 8192;   // [y][i]
    int t = threadIdx.x;
    for (int c = 0; c < 32; ++c) {
        int gI = (c << 8) + t;              // gI = y*32 + i
        int yy = gI >> 5, ii = gI & 31;
        float2 v = src[gI];
        int sw = ii * 256 + ((yy + ii) & 255);     // swizzled (conflict-free, no pad)
        xr[sw] = v.x; xi[sw] = v.y;
    }
    __syncthreads();

    int i = t & 31, mg = t >> 5;            // modes m = mg + 8k, k=0..3
    float ar[4] = {0, 0, 0, 0}, ai[4] = {0, 0, 0, 0};
    float tr[4], ti[4], wr[4], wi[4];
#pragma unroll
    for (int k = 0; k < 4; ++k) {
        int m = mg + 8 * k;
        int kh = (m < 16) ? m : m - 32;     // kh in {-16..15}
        sincosf(-TWO_PI * (float)kh / 256.f, &wi[k], &wr[k]);
        tr[k] = 1.f; ti[k] = 0.f;
    }
    for (int yy = 0; yy < 256; ++yy) {
        int idx = i * 256 + ((yy + i) & 255);
        float Xr = xr[idx], Xi = xi[idx];
#pragma unroll
        for (int k = 0; k < 4; ++k) {
            ar[k] = fmaf(Xr, tr[k], ar[k]); ar[k] = fmaf(-Xi, ti[k], ar[k]);
            ai[k] = fmaf(Xr, ti[k], ai[k]); ai[k] = fmaf(Xi, tr[k], ai[k]);
            float nr = tr[k] * wr[k] - ti[k] * wi[k];
            float ni = tr[k] * wi[k] + ti[k] * wr[k];
            tr[k] = nr; ti[k] = ni;
        }
    }
#pragma unroll
    for (int k = 0; k < 4; ++k) {
        int m = mg + 8 * k;
        xft[(size_t)b * 17408 + (size_t)m * 544 + (size_t)kw * 32 + i] =
            make_float2(ar[k], ai[k]);
    }
}

// ---------------- K3: per-mode complex channel mixing -------------
// grid = 32*17 blocks (one per (m,kw)), 256 threads
__global__ __launch_bounds__(256) void k3_mix(const float2* __restrict__ xft,
                                              const float* __restrict__ w1r,
                                              const float* __restrict__ w1i,
                                              const float* __restrict__ w2r,
                                              const float* __restrict__ w2i,
                                              float2* __restrict__ oft) {
    __shared__ float wrl[1024];             // [i][o]
    __shared__ float wil[1024];
    __shared__ float2 xbl[512];             // [b][i]
    int bk = blockIdx.x;                    // m*17 + kw
    int m = bk / 17, kw = bk - m * 17;
    const float* wr_g; const float* wi_g; int h;
    if (m < 16) { wr_g = w1r; wi_g = w1i; h = m; }
    else        { wr_g = w2r; wi_g = w2i; h = m - 16; }
    int t = threadIdx.x;
#pragma unroll
    for (int c = 0; c < 4; ++c) {
        int u = (c << 8) + t;               // u = i*32 + o
        int ii = u >> 5, o = u & 31;
        size_t gi = ((size_t)(ii * 32 + o) * 16 + h) * 17 + kw;  // (CIN,COUT,EM0,EM1)
        wrl[u] = wr_g[gi]; wil[u] = wi_g[gi];
    }
#pragma unroll
    for (int c = 0; c < 2; ++c) {
        int u = (c << 8) + t;               // u = b*32 + i
        int bb = u >> 5, ii = u & 31;
        xbl[u] = xft[(size_t)bb * 17408 + (size_t)m * 544 + (size_t)kw * 32 + ii];
    }
    __syncthreads();
    int o = t & 31, bg = t >> 5;
#pragma unroll
    for (int r = 0; r < 2; ++r) {
        int bb = bg + 8 * r;
        float ar = 0.f, ai = 0.f;
#pragma unroll
        for (int ii = 0; ii < 32; ++ii) {
            float2 xv = xbl[bb * 32 + ii];  // broadcast across o-lanes
            float wr_ = wrl[ii * 32 + o], wi_ = wil[ii * 32 + o];
            ar = fmaf(xv.x, wr_, ar); ar = fmaf(-xv.y, wi_, ar);
            ai = fmaf(xv.x, wi_, ai); ai = fmaf(xv.y, wr_, ai);
        }
        oft[(size_t)bb * 17408 + (size_t)m * 544 + (size_t)kw * 32 + o] =
            make_float2(ar, ai);
    }
}

// ---------------- K4: inverse H-DFT (32 modes -> 256 y) -------------
// grid = B*17 blocks, thread = y. T layout: [b][y][kw][o] f2
__global__ __launch_bounds__(256) void k4_invH(const float2* __restrict__ oft,
                                               float2* __restrict__ T) {
    __shared__ float2 ol[1024];             // [m][o]
    int bk = blockIdx.x;                    // b*17 + kw
    int b = bk / 17, kw = bk - b * 17;
    int t = threadIdx.x;
#pragma unroll
    for (int c = 0; c < 4; ++c) {
        int u = (c << 8) + t;
        int m = u >> 5, o = u & 31;
        ol[u] = oft[(size_t)b * 17408 + (size_t)m * 544 + (size_t)kw * 32 + o];
    }
    __syncthreads();
    int y = t;
    float ur, ui;
    sincosf(TWO_PI * (float)y / 256.f, &ui, &ur);   // u = e^{+2pi i y/256}
    float accr[32], acci[32];
#pragma unroll
    for (int o = 0; o < 32; ++o) { accr[o] = 0.f; acci[o] = 0.f; }
    float tr = 1.f, ti = 0.f;               // twiddle = u^kh
    for (int m = 0; m < 32; ++m) {
        if (m == 16) ti = -ti;              // jump kh=+16 -> kh=-16 (conjugate)
#pragma unroll
        for (int o = 0; o < 32; ++o) {
            float2 v = ol[m * 32 + o];      // uniform -> LDS broadcast
            accr[o] = fmaf(v.x, tr, accr[o]); accr[o] = fmaf(-v.y, ti, accr[o]);
            acci[o] = fmaf(v.x, ti, acci[o]); acci[o] = fmaf(v.y, tr, acci[o]);
        }
        float nr = tr * ur - ti * ui, ni = tr * ui + ti * ur;
        tr = nr; ti = ni;
    }
    float2* dst = T + ((size_t)(b * 256 + y) * 17 + kw) * 32;
#pragma unroll
    for (int o = 0; o < 32; ++o) dst[o] = make_float2(accr[o], acci[o]);
}

// ---------------- K5: inverse W reconstruction + bias -------------
// grid = B*H blocks (one per (b,y) row), thread = x
__global__ __launch_bounds__(256) void k5_invW(const float2* __restrict__ T,
                                               const float* __restrict__ bias,
                                               float* __restrict__ out) {
    __shared__ float2 tl[544];              // [kw][o]
    __shared__ float bl[32];
    int blk = blockIdx.x;                   // b*256 + y
    int t = threadIdx.x;
    const float2* src = T + (size_t)blk * 544;
    for (int u = t; u < 544; u += 256) tl[u] = src[u];
    if (t < 32) bl[t] = bias[t];
    __syncthreads();
    int x = t;
    float ur, ui;
    sincosf(TWO_PI * (float)x / 256.f, &ui, &ur);
    float acc[32];
#pragma unroll
    for (int o = 0; o < 32; ++o) acc[o] = tl[o].x + bl[o];  // Re(T0) (+ bias)
    float tr = ur, ti = ui;                 // kw=1 twiddle
    for (int kw = 1; kw < 17; ++kw) {
        float c2 = 2.f * tr, s2 = 2.f * ti;
#pragma unroll
        for (int o = 0; o < 32; ++o) {
            float2 v = tl[kw * 32 + o];     // uniform -> LDS broadcast
            acc[o] = fmaf(v.x, c2, acc[o]);
            acc[o] = fmaf(-v.y, s2, acc[o]);
        }
        float nr = tr * ur - ti * ui, ni = tr * ui + ti * ur;
        tr = nr; ti = ni;
    }
    float* dst = out + ((size_t)blk * 256 + x) * 32;
#pragma unroll
    for (int o = 0; o < 32; o += 4) {
        float4 v = make_float4(acc[o], acc[o + 1], acc[o + 2], acc[o + 3]);
        *(float4*)(dst + o) = v;
    }
}

extern "C" void kernel_launch(void* const* d_in, const int* in_sizes, int n_in,
                              void* d_out, int out_size, void* d_ws, size_t ws_size,
                              hipStream_t stream) {
    const float* x    = (const float*)d_in[0];
    const float* w1r  = (const float*)d_in[1];
    const float* w1i  = (const float*)d_in[2];
    const float* w2r  = (const float*)d_in[3];
    const float* w2i  = (const float*)d_in[4];
    const float* bias = (const float*)d_in[5];
    float* out = (float*)d_out;

    char* ws = (char*)d_ws;
    // Xw: B*17*256*32 f2 = 2,228,224 f2 = 17,825,792 B  (aliased with T: Xw dead after K2)
    float2* Xw  = (float2*)ws;
    float2* T   = Xw;
    float2* xft = (float2*)(ws + 17825792);               // 278,528 f2 = 2,228,224 B
    float2* oft = (float2*)(ws + 17825792 + 2228224);     // 278,528 f2
    // total ws use: ~22.3 MB

    k1_fwdW<<<NB * NH, 256, 0, stream>>>(x, Xw);
    k2_fwdH<<<NB * EM1, 256, 0, stream>>>(Xw, xft);
    k3_mix <<<32 * EM1, 256, 0, stream>>>(xft, w1r, w1i, w2r, w2i, oft);
    k4_invH<<<NB * EM1, 256, 0, stream>>>(oft, T);
    k5_invW<<<NB * NH, 256, 0, stream>>>(T, bias, out);
}

// Round 2
// 326.848 us; speedup vs baseline: 1.2427x; 1.2427x over previous
//
#include <hip/hip_runtime.h>

// B=16, H=256, W=256, CIN=COUT=32, kept modes: kh in {0..15,-16..-1}, kw in 0..16
#define NB 16
#define NH 256
#define EM1 17
#define TWO_PI 6.283185307179586f

__device__ __forceinline__ void cmul_upd(float& tr, float& ti, float wr, float wi) {
    float nr = tr * wr - ti * wi;
    float ni = tr * wi + ti * wr;
    tr = nr; ti = ni;
}

// ---------------- K1: forward W-DFT (256 -> 17 bins), scale 1/65536 ----------------
// 1024 blocks x 256 thr; block = 4 rows (b,y); wave r handles row r.
// lane l (0..63): g = l>>3 (bins g and g+8), cg = l&7 (channel quad)
// Xw layout: [b][kw][y][i] float2
__global__ __launch_bounds__(256) void k1_fwdW(const float* __restrict__ x,
                                               float2* __restrict__ Xw) {
    __shared__ __align__(16) float xs[4 * 64 * 32];   // [r][x64][i32], 32 KB
    const int t = threadIdx.x;
    const int r = t >> 6;
    const int l = t & 63;
    const int g = l >> 3;
    const int cg = l & 7;
    const int row = blockIdx.x * 4 + r;   // b*256 + y
    const int b = row >> 8, y = row & 255;

    float wc0, ws0, wc1, ws1;
    sincosf(-TWO_PI * (float)g * (1.f / 256.f), &ws0, &wc0);
    sincosf(-TWO_PI * (float)(g + 8) * (1.f / 256.f), &ws1, &wc1);
    float t0r = 1.f, t0i = 0.f, t1r = 1.f, t1i = 0.f;
    float a0r[4] = {0,0,0,0}, a0i[4] = {0,0,0,0};
    float a1r[4] = {0,0,0,0}, a1i[4] = {0,0,0,0};
    float pr[4]  = {0,0,0,0}, pq[4]  = {0,0,0,0};     // kw16 partial (re, im)

    // e^{-2*pi*i*j/16} LUT (compile-time consts -> SGPR operands)
    const float K16C[8] = {1.f, 0.92387953251f, 0.70710678119f, 0.38268343236f,
                           0.f, -0.38268343236f, -0.70710678119f, -0.92387953251f};
    const float K16S[8] = {0.f, -0.38268343236f, -0.70710678119f, -0.92387953251f,
                           -1.f, -0.92387953251f, -0.70710678119f, -0.38268343236f};

    const float4* gsrc = (const float4*)(x + (size_t)blockIdx.x * 32768); // 4 rows * 8192 f

    #pragma unroll 1
    for (int c = 0; c < 4; ++c) {
        __syncthreads();
        #pragma unroll
        for (int q = 0; q < 8; ++q) {
            int v = q * 256 + t;                 // f4 id: rr*512 + x*8 + quad
            int rr = v >> 9, id = v & 511;
            ((float4*)xs)[v] = gsrc[(size_t)rr * 2048 + c * 512 + id];
        }
        __syncthreads();
        const float* xp = xs + r * 2048 + cg * 4;
        #pragma unroll
        for (int xx = 0; xx < 64; ++xx) {
            float4 v = *(const float4*)(xp + xx * 32);
            float vv[4] = {v.x, v.y, v.z, v.w};
            #pragma unroll
            for (int k = 0; k < 4; ++k) {
                a0r[k] = fmaf(vv[k], t0r, a0r[k]);
                a0i[k] = fmaf(vv[k], t0i, a0i[k]);
                a1r[k] = fmaf(vv[k], t1r, a1r[k]);
                a1i[k] = fmaf(vv[k], t1i, a1i[k]);
            }
            cmul_upd(t0r, t0i, wc0, ws0);
            cmul_upd(t1r, t1i, wc1, ws1);
        }
        // kw16 side-pass: lane covers x = c*64 + g*8 + j  (e^{-2pi i x/16} = (-1)^g * LUT[j])
        const float* kp = xs + r * 2048 + g * 256 + cg * 4;
        #pragma unroll
        for (int j = 0; j < 8; ++j) {
            float4 v = *(const float4*)(kp + j * 32);
            float vv[4] = {v.x, v.y, v.z, v.w};
            const float cj = K16C[j], sj = K16S[j];
            #pragma unroll
            for (int k = 0; k < 4; ++k) {
                pr[k] = fmaf(vv[k], cj, pr[k]);
                pq[k] = fmaf(vv[k], sj, pq[k]);
            }
        }
    }

    const float sc = 1.0f / 65536.0f;
    size_t base0 = (((size_t)b * 17 + g) * 256 + y) * 32 + cg * 4;
    *(float4*)(Xw + base0)     = make_float4(a0r[0]*sc, a0i[0]*sc, a0r[1]*sc, a0i[1]*sc);
    *(float4*)(Xw + base0 + 2) = make_float4(a0r[2]*sc, a0i[2]*sc, a0r[3]*sc, a0i[3]*sc);
    size_t base1 = (((size_t)b * 17 + g + 8) * 256 + y) * 32 + cg * 4;
    *(float4*)(Xw + base1)     = make_float4(a1r[0]*sc, a1i[0]*sc, a1r[1]*sc, a1i[1]*sc);
    *(float4*)(Xw + base1 + 2) = make_float4(a1r[2]*sc, a1i[2]*sc, a1r[3]*sc, a1i[3]*sc);

    // kw16: apply (-1)^g, reduce over g (lane bits 3..5), write from g==0 lanes
    float sg = (g & 1) ? -1.f : 1.f;
    #pragma unroll
    for (int k = 0; k < 4; ++k) { pr[k] *= sg; pq[k] *= sg; }
    #pragma unroll
    for (int m = 8; m <= 32; m <<= 1) {
        #pragma unroll
        for (int k = 0; k < 4; ++k) {
            pr[k] += __shfl_xor(pr[k], m);
            pq[k] += __shfl_xor(pq[k], m);
        }
    }
    if (g == 0) {
        size_t b16 = (((size_t)b * 17 + 16) * 256 + y) * 32 + cg * 4;
        *(float4*)(Xw + b16)     = make_float4(pr[0]*sc, pq[0]*sc, pr[1]*sc, pq[1]*sc);
        *(float4*)(Xw + b16 + 2) = make_float4(pr[2]*sc, pq[2]*sc, pr[3]*sc, pq[3]*sc);
    }
}

// ---------------- K2: forward H-DFT at 32 kept kh rows ----------------
// grid = 16*17*2 = 544 blocks: (b, kw, i-half). xft: [b][m][kw][i] f2
__global__ __launch_bounds__(256) void k2_fwdH(const float2* __restrict__ Xw,
                                               float2* __restrict__ xft) {
    __shared__ __align__(16) float2 xsh[256 * 16];    // [y][i-half], 32 KB
    const int t = threadIdx.x;
    const int bk = blockIdx.x;
    const int b = bk / 34;
    const int rem = bk - b * 34;
    const int kw = rem >> 1, ih = rem & 1;
    const float2* src = Xw + ((size_t)(b * 17 + kw) * 256) * 32 + ih * 16;
    #pragma unroll
    for (int q = 0; q < 8; ++q) {
        int v = q * 256 + t;                 // f4: y*8 + quad
        int yy = v >> 3, quad = v & 7;
        ((float4*)xsh)[v] = *(const float4*)(src + (size_t)yy * 32 + quad * 2);
    }
    __syncthreads();
    const int m = t & 31, ip = t >> 5;       // i = ih*16 + ip*2 + {0,1}
    const int kh = (m < 16) ? m : m - 32;
    float wc, ws; sincosf(-TWO_PI * (float)kh * (1.f / 256.f), &ws, &wc);
    float tr = 1.f, ti = 0.f;
    float a0r = 0.f, a0i = 0.f, a1r = 0.f, a1i = 0.f;
    const float* xp = (const float*)xsh + ip * 4;
    #pragma unroll 8
    for (int yy = 0; yy < 256; ++yy) {
        float4 v = *(const float4*)(xp + yy * 32);
        a0r = fmaf(v.x, tr, a0r); a0r = fmaf(-v.y, ti, a0r);
        a0i = fmaf(v.x, ti, a0i); a0i = fmaf(v.y, tr, a0i);
        a1r = fmaf(v.z, tr, a1r); a1r = fmaf(-v.w, ti, a1r);
        a1i = fmaf(v.z, ti, a1i); a1i = fmaf(v.w, tr, a1i);
        cmul_upd(tr, ti, wc, ws);
    }
    size_t o = ((size_t)b * 32 + m) * 544 + (size_t)kw * 32 + ih * 16 + ip * 2;
    *(float4*)(xft + o) = make_float4(a0r, a0i, a1r, a1i);
}

// ---------------- K3: per-mode complex channel mixing ----------------
__global__ __launch_bounds__(256) void k3_mix(const float2* __restrict__ xft,
                                              const float* __restrict__ w1r,
                                              const float* __restrict__ w1i,
                                              const float* __restrict__ w2r,
                                              const float* __restrict__ w2i,
                                              float2* __restrict__ oft) {
    __shared__ float wrl[1024];             // [i][o]
    __shared__ float wil[1024];
    __shared__ float2 xbl[512];             // [b][i]
    int bk = blockIdx.x;                    // m*17 + kw
    int m = bk / 17, kw = bk - m * 17;
    const float* wr_g; const float* wi_g; int h;
    if (m < 16) { wr_g = w1r; wi_g = w1i; h = m; }
    else        { wr_g = w2r; wi_g = w2i; h = m - 16; }
    int t = threadIdx.x;
#pragma unroll
    for (int c = 0; c < 4; ++c) {
        int u = (c << 8) + t;               // u = i*32 + o
        int ii = u >> 5, o = u & 31;
        size_t gi = ((size_t)(ii * 32 + o) * 16 + h) * 17 + kw;  // (CIN,COUT,16,17)
        wrl[u] = wr_g[gi]; wil[u] = wi_g[gi];
    }
#pragma unroll
    for (int c = 0; c < 2; ++c) {
        int u = (c << 8) + t;               // u = b*32 + i
        int bb = u >> 5, ii = u & 31;
        xbl[u] = xft[(size_t)bb * 17408 + (size_t)m * 544 + (size_t)kw * 32 + ii];
    }
    __syncthreads();
    int o = t & 31, bg = t >> 5;
#pragma unroll
    for (int rr = 0; rr < 2; ++rr) {
        int bb = bg + 8 * rr;
        float ar = 0.f, ai = 0.f;
#pragma unroll
        for (int ii = 0; ii < 32; ++ii) {
            float2 xv = xbl[bb * 32 + ii];
            float wr_ = wrl[ii * 32 + o], wi_ = wil[ii * 32 + o];
            ar = fmaf(xv.x, wr_, ar); ar = fmaf(-xv.y, wi_, ar);
            ai = fmaf(xv.x, wi_, ai); ai = fmaf(xv.y, wr_, ai);
        }
        oft[(size_t)bb * 17408 + (size_t)m * 544 + (size_t)kw * 32 + o] =
            make_float2(ar, ai);
    }
}

// ---------------- K4: inverse H-DFT (32 modes -> 256 y) ----------------
// grid = 16*17*2 = 544 blocks: (b, kw, o-half); thread = y. T: [b][y][kw][o] f2
__global__ __launch_bounds__(256) void k4_invH(const float2* __restrict__ oft,
                                               float2* __restrict__ T) {
    __shared__ __align__(16) float2 ol[32 * 16];      // [m][o-half], 4 KB
    const int t = threadIdx.x;
    const int bk = blockIdx.x;
    const int b = bk / 34;
    const int rem = bk - b * 34;
    const int kw = rem >> 1, oh = rem & 1;
    {
        int mm = t >> 3, quad = t & 7;       // 256 f4 = 512 f2
        ((float4*)ol)[t] = *(const float4*)(oft + (size_t)b * 17408 +
                                            (size_t)mm * 544 + (size_t)kw * 32 + oh * 16 + quad * 2);
    }
    __syncthreads();
    const int y = t;
    float uc, us; sincosf(TWO_PI * (float)y * (1.f / 256.f), &us, &uc);
    float tr = 1.f, ti = 0.f;
    float ar[16], ai[16];
    #pragma unroll
    for (int o = 0; o < 16; ++o) { ar[o] = 0.f; ai[o] = 0.f; }
    for (int m = 0; m < 32; ++m) {
        if (m == 16) ti = -ti;               // kh jumps +16 -> -16
        #pragma unroll
        for (int o2 = 0; o2 < 8; ++o2) {
            float4 v = *(const float4*)((const float*)ol + m * 32 + o2 * 4);
            int o = o2 * 2;
            ar[o]   = fmaf(v.x, tr, ar[o]);   ar[o]   = fmaf(-v.y, ti, ar[o]);
            ai[o]   = fmaf(v.x, ti, ai[o]);   ai[o]   = fmaf(v.y, tr, ai[o]);
            ar[o+1] = fmaf(v.z, tr, ar[o+1]); ar[o+1] = fmaf(-v.w, ti, ar[o+1]);
            ai[o+1] = fmaf(v.z, ti, ai[o+1]); ai[o+1] = fmaf(v.w, tr, ai[o+1]);
        }
        cmul_upd(tr, ti, uc, us);
    }
    float2* dst = T + ((size_t)(b * 256 + y) * 17 + kw) * 32 + oh * 16;
    #pragma unroll
    for (int o2 = 0; o2 < 8; ++o2) {
        *(float4*)(dst + o2 * 2) =
            make_float4(ar[o2*2], ai[o2*2], ar[o2*2+1], ai[o2*2+1]);
    }
}

// ---------------- K5: inverse W reconstruction + bias ----------------
// grid = 4096 blocks (one per (b,y)); lane = (x-quad, o-oct)
__global__ __launch_bounds__(256) void k5_invW(const float2* __restrict__ T,
                                               const float* __restrict__ bias,
                                               float* __restrict__ out) {
    __shared__ __align__(16) float2 tl[544];          // [kw][o]
    __shared__ float bl[32];
    const int t = threadIdx.x;
    const int blk = blockIdx.x;                       // b*256 + y
    const float4* src4 = (const float4*)(T + (size_t)blk * 544);
    for (int u = t; u < 272; u += 256) ((float4*)tl)[u] = src4[u];
    if (t < 32) bl[t] = bias[t];
    __syncthreads();
    const int o8 = t & 3, xq = t >> 2;                // o base = o8*8, x = xq*4 + k
    float c0, s0; sincosf(TWO_PI * (float)(xq * 4) * (1.f / 256.f), &s0, &c0);
    const float CC = 0.99969881869620422f, SS = 0.02454122852291229f;  // e^{2pi i/256}
    float ur[4], ui[4];
    ur[0] = c0; ui[0] = s0;
    #pragma unroll
    for (int k = 1; k < 4; ++k) {
        ur[k] = ur[k-1] * CC - ui[k-1] * SS;
        ui[k] = ur[k-1] * SS + ui[k-1] * CC;
    }
    float tr_[4], ti_[4];
    #pragma unroll
    for (int k = 0; k < 4; ++k) { tr_[k] = ur[k]; ti_[k] = ui[k]; }
    float acc[4][8];
    #pragma unroll
    for (int k = 0; k < 4; ++k)
        #pragma unroll
        for (int o = 0; o < 8; ++o) acc[k][o] = 0.f;
    #pragma unroll 4
    for (int kw = 1; kw < 17; ++kw) {
        #pragma unroll
        for (int o2 = 0; o2 < 4; ++o2) {
            float4 v = *(const float4*)((const float*)tl + kw * 64 + o8 * 16 + o2 * 4);
            #pragma unroll
            for (int k = 0; k < 4; ++k) {
                acc[k][o2*2]   = fmaf(v.x, tr_[k], acc[k][o2*2]);
                acc[k][o2*2]   = fmaf(-v.y, ti_[k], acc[k][o2*2]);
                acc[k][o2*2+1] = fmaf(v.z, tr_[k], acc[k][o2*2+1]);
                acc[k][o2*2+1] = fmaf(-v.w, ti_[k], acc[k][o2*2+1]);
            }
        }
        #pragma unroll
        for (int k = 0; k < 4; ++k) cmul_upd(tr_[k], ti_[k], ur[k], ui[k]);
    }
    float base[8];
    #pragma unroll
    for (int o = 0; o < 8; ++o) {
        int og = o8 * 8 + o;
        base[o] = tl[og].x + bl[og];                  // Re(T0) + bias
    }
    float* orow = out + (size_t)blk * 8192;
    #pragma unroll
    for (int k = 0; k < 4; ++k) {
        int xx = xq * 4 + k;
        float res[8];
        #pragma unroll
        for (int o = 0; o < 8; ++o) res[o] = fmaf(2.f, acc[k][o], base[o]);
        float* dst = orow + xx * 32 + o8 * 8;
        *(float4*)(dst)     = make_float4(res[0], res[1], res[2], res[3]);
        *(float4*)(dst + 4) = make_float4(res[4], res[5], res[6], res[7]);
    }
}

extern "C" void kernel_launch(void* const* d_in, const int* in_sizes, int n_in,
                              void* d_out, int out_size, void* d_ws, size_t ws_size,
                              hipStream_t stream) {
    const float* x    = (const float*)d_in[0];
    const float* w1r  = (const float*)d_in[1];
    const float* w1i  = (const float*)d_in[2];
    const float* w2r  = (const float*)d_in[3];
    const float* w2i  = (const float*)d_in[4];
    const float* bias = (const float*)d_in[5];
    float* out = (float*)d_out;

    char* ws = (char*)d_ws;
    // Xw: 16*17*256*32 f2 = 17,825,792 B  (aliased with T: Xw dead after K2)
    float2* Xw  = (float2*)ws;
    float2* T   = Xw;
    float2* xft = (float2*)(ws + 17825792);               // 2,228,224 B
    float2* oft = (float2*)(ws + 17825792 + 2228224);     // 2,228,224 B

    k1_fwdW<<<NB * NH / 4, 256, 0, stream>>>(x, Xw);
    k2_fwdH<<<NB * EM1 * 2, 256, 0, stream>>>(Xw, xft);
    k3_mix <<<32 * EM1, 256, 0, stream>>>(xft, w1r, w1i, w2r, w2i, oft);
    k4_invH<<<NB * EM1 * 2, 256, 0, stream>>>(oft, T);
    k5_invW<<<NB * NH, 256, 0, stream>>>(T, bias, out);
}

// Round 3
// 315.149 us; speedup vs baseline: 1.2888x; 1.0371x over previous
//
#include <hip/hip_runtime.h>

// B=16, H=256, W=256, CIN=COUT=32, kept modes: kh in {0..15,-16..-1}, kw in 0..16
#define NB 16
#define NH 256
#define EM1 17
#define TWO_PI 6.283185307179586f

typedef short short8 __attribute__((ext_vector_type(8)));
typedef float floatx4 __attribute__((ext_vector_type(4)));

__device__ __forceinline__ unsigned f2b(float x){ union{float f; unsigned u;} v; v.f=x; return v.u; }
__device__ __forceinline__ float b2f(unsigned u){ union{float f; unsigned u;} v; v.u=u; return v.f; }

__device__ __forceinline__ void cmul_upd(float& tr, float& ti, float wr, float wi) {
    float nr = tr * wr - ti * wi;
    float ni = tr * wi + ti * wr;
    tr = nr; ti = ni;
}

// ---------------- K1: forward W-DFT via MFMA bf16x2 ----------------
// Per (b,y)-row GEMM: D[i][n] = sum_x A[i][x] * B[x][n],  M=32, K=256, N=34
//   B[x][2kw]   =  cos(2pi kw x/256) / 65536
//   B[x][2kw+1] = -sin(2pi kw x/256) / 65536
// Grid 512 blocks x 256 thr (4 waves); block handles 8 rows; 2 blocks/CU.
// Wave w: mt = w&1 (i-tile), g = w>>1 (g0: n-tiles {0,1}, g1: n-tile {2}).
// A staged per row in LDS as pre-interleaved fragments (hi/lo bf16 split).
// Xw layout (float view): [b][kw][y][i*2+reim]
__global__ __launch_bounds__(256, 2) void k1_fwdW_mfma(const float* __restrict__ x,
                                                       float* __restrict__ Xw) {
    // 32 frags x 64 lanes x 8 shorts = 16384 shorts = 32 KB
    // frag_id = h*16 + ks*2 + mt   (h: 0=hi,1=lo; ks 0..7; mt 0..1)
    __shared__ __align__(16) short alds[16384];
    const int t = threadIdx.x;
    const int w = t >> 6;
    const int l = t & 63;
    const int mt = w & 1;
    const int g  = w >> 1;
    const int nn = (g == 0) ? 2 : 1;   // how many n-tiles this wave owns

    // ---- build B twiddle fragments in registers (shared across all rows) ----
    // B-operand layout: lane l holds B[k][n] with n = l&15 (+16*nt), k = (l>>4)*8 + j
    short8 Bh[2][8], Bl[2][8];
    const float sc = 1.0f / 65536.0f;          // norm="forward" 1/(H*W)
    #pragma unroll
    for (int u = 0; u < 2; ++u) {
        const int nt  = (g == 0) ? u : 2;
        const int n   = nt * 16 + (l & 15);
        const int kwv = n >> 1;
        const int par = n & 1;
        const bool live = (u < nn) && (n < 34);
        const float dth = (TWO_PI / 256.f) * (float)kwv;
        #pragma unroll
        for (int ks = 0; ks < 8; ++ks) {
            const int k0 = ks * 32 + (l >> 4) * 8;
            float s, c; sincosf(dth * (float)k0, &s, &c);
            float sd, cd; sincosf(dth, &sd, &cd);
            short8 vh, vl;
            #pragma unroll
            for (int j = 0; j < 8; ++j) {
                float v = live ? ((par ? -s : c) * sc) : 0.f;
                unsigned ub = f2b(v);
                short h16 = (short)(ub >> 16);
                float rres = v - b2f(ub & 0xFFFF0000u);
                short l16 = (short)(f2b(rres) >> 16);
                vh[j] = h16; vl[j] = l16;
                float ncv = c * cd - s * sd, nsv = c * sd + s * cd;
                c = ncv; s = nsv;
            }
            Bh[u][ks] = vh; Bl[u][ks] = vl;
        }
    }

    const int i   = t & 31;        // staging channel
    const int slot = t >> 5;       // staging x-pair slot
    const int i15 = i & 15, imt = i >> 4;
    const int i15l = l & 15, ql = l >> 4;

    for (int ir = 0; ir < 8; ++ir) {
        const int row = blockIdx.x * 8 + ir;     // b*256 + y
        const int b = row >> 8, y = row & 255;
        __syncthreads();                         // LDS reuse guard
        // ---- stage row: global [x][i] fp32 -> LDS A-fragments bf16 hi/lo ----
        {
            const float* rp = x + (size_t)row * 8192;
            unsigned* al32 = (unsigned*)alds;
            #pragma unroll
            for (int c = 0; c < 16; ++c) {
                const int xp = slot + (c << 3);          // x-pair index 0..127, k = 2*xp
                float v0 = rp[xp * 64 + i];
                float v1 = rp[xp * 64 + 32 + i];
                unsigned u0 = f2b(v0), u1 = f2b(v1);
                unsigned hi = (u0 >> 16) | (u1 & 0xFFFF0000u);
                float r0 = v0 - b2f(u0 & 0xFFFF0000u);
                float r1 = v1 - b2f(u1 & 0xFFFF0000u);
                unsigned lo = (f2b(r0) >> 16) | (f2b(r1) & 0xFFFF0000u);
                const int ks = xp >> 4, q = (xp & 15) >> 2, dw = xp & 3;
                const int base = (ks * 2 + imt) * 256 + (q * 16 + i15) * 4 + dw;
                al32[base] = hi;
                al32[base + 16 * 256] = lo;              // h=1 frags start at +16 KB
            }
        }
        __syncthreads();
        // ---- MFMA K-loop ----
        floatx4 acc0 = {0.f, 0.f, 0.f, 0.f};
        floatx4 acc1 = {0.f, 0.f, 0.f, 0.f};
        #pragma unroll
        for (int ks = 0; ks < 8; ++ks) {
            const short8 ah = *(const short8*)(alds + ((ks * 2 + mt) * 512) + l * 8);
            const short8 al = *(const short8*)(alds + ((16 + ks * 2 + mt) * 512) + l * 8);
            acc0 = __builtin_amdgcn_mfma_f32_16x16x32_bf16(ah, Bh[0][ks], acc0, 0, 0, 0);
            acc0 = __builtin_amdgcn_mfma_f32_16x16x32_bf16(ah, Bl[0][ks], acc0, 0, 0, 0);
            acc0 = __builtin_amdgcn_mfma_f32_16x16x32_bf16(al, Bh[0][ks], acc0, 0, 0, 0);
            if (nn == 2) {
                acc1 = __builtin_amdgcn_mfma_f32_16x16x32_bf16(ah, Bh[1][ks], acc1, 0, 0, 0);
                acc1 = __builtin_amdgcn_mfma_f32_16x16x32_bf16(ah, Bl[1][ks], acc1, 0, 0, 0);
                acc1 = __builtin_amdgcn_mfma_f32_16x16x32_bf16(al, Bh[1][ks], acc1, 0, 0, 0);
            }
        }
        // ---- store: D lane l reg r -> (i = mt*16 + (l>>4)*4 + r, n = nt*16 + (l&15)) ----
        #pragma unroll
        for (int u = 0; u < 2; ++u) {
            if (u >= nn) break;
            const int nt = (g == 0) ? u : 2;
            const int n = nt * 16 + i15l;
            if (n < 34) {
                const int kwv = n >> 1, par = n & 1;
                float* dst = Xw + (((size_t)(b * 17 + kwv) * 256 + y) * 64) + par;
                const floatx4 a = (u == 0) ? acc0 : acc1;
                #pragma unroll
                for (int r = 0; r < 4; ++r) {
                    const int ii = mt * 16 + ql * 4 + r;
                    dst[ii * 2] = a[r];
                }
            }
        }
    }
}

// ---------------- K2: forward H-DFT at 32 kept kh rows ----------------
// grid = 16*17*2 = 544 blocks: (b, kw, i-half). xft: [b][m][kw][i] f2
__global__ __launch_bounds__(256) void k2_fwdH(const float2* __restrict__ Xw,
                                               float2* __restrict__ xft) {
    __shared__ __align__(16) float2 xsh[256 * 16];    // [y][i-half], 32 KB
    const int t = threadIdx.x;
    const int bk = blockIdx.x;
    const int b = bk / 34;
    const int rem = bk - b * 34;
    const int kw = rem >> 1, ih = rem & 1;
    const float2* src = Xw + ((size_t)(b * 17 + kw) * 256) * 32 + ih * 16;
    #pragma unroll
    for (int q = 0; q < 8; ++q) {
        int v = q * 256 + t;                 // f4: y*8 + quad
        int yy = v >> 3, quad = v & 7;
        ((float4*)xsh)[v] = *(const float4*)(src + (size_t)yy * 32 + quad * 2);
    }
    __syncthreads();
    const int m = t & 31, ip = t >> 5;       // i = ih*16 + ip*2 + {0,1}
    const int kh = (m < 16) ? m : m - 32;
    float wc, ws; sincosf(-TWO_PI * (float)kh * (1.f / 256.f), &ws, &wc);
    float tr = 1.f, ti = 0.f;
    float a0r = 0.f, a0i = 0.f, a1r = 0.f, a1i = 0.f;
    const float* xp = (const float*)xsh + ip * 4;
    #pragma unroll 8
    for (int yy = 0; yy < 256; ++yy) {
        float4 v = *(const float4*)(xp + yy * 32);
        a0r = fmaf(v.x, tr, a0r); a0r = fmaf(-v.y, ti, a0r);
        a0i = fmaf(v.x, ti, a0i); a0i = fmaf(v.y, tr, a0i);
        a1r = fmaf(v.z, tr, a1r); a1r = fmaf(-v.w, ti, a1r);
        a1i = fmaf(v.z, ti, a1i); a1i = fmaf(v.w, tr, a1i);
        cmul_upd(tr, ti, wc, ws);
    }
    size_t o = ((size_t)b * 32 + m) * 544 + (size_t)kw * 32 + ih * 16 + ip * 2;
    *(float4*)(xft + o) = make_float4(a0r, a0i, a1r, a1i);
}

// ---------------- K3: per-mode complex channel mixing ----------------
__global__ __launch_bounds__(256) void k3_mix(const float2* __restrict__ xft,
                                              const float* __restrict__ w1r,
                                              const float* __restrict__ w1i,
                                              const float* __restrict__ w2r,
                                              const float* __restrict__ w2i,
                                              float2* __restrict__ oft) {
    __shared__ float wrl[1024];             // [i][o]
    __shared__ float wil[1024];
    __shared__ float2 xbl[512];             // [b][i]
    int bk = blockIdx.x;                    // m*17 + kw
    int m = bk / 17, kw = bk - m * 17;
    const float* wr_g; const float* wi_g; int h;
    if (m < 16) { wr_g = w1r; wi_g = w1i; h = m; }
    else        { wr_g = w2r; wi_g = w2i; h = m - 16; }
    int t = threadIdx.x;
#pragma unroll
    for (int c = 0; c < 4; ++c) {
        int u = (c << 8) + t;               // u = i*32 + o
        int ii = u >> 5, o = u & 31;
        size_t gi = ((size_t)(ii * 32 + o) * 16 + h) * 17 + kw;  // (CIN,COUT,16,17)
        wrl[u] = wr_g[gi]; wil[u] = wi_g[gi];
    }
#pragma unroll
    for (int c = 0; c < 2; ++c) {
        int u = (c << 8) + t;               // u = b*32 + i
        int bb = u >> 5, ii = u & 31;
        xbl[u] = xft[(size_t)bb * 17408 + (size_t)m * 544 + (size_t)kw * 32 + ii];
    }
    __syncthreads();
    int o = t & 31, bg = t >> 5;
#pragma unroll
    for (int rr = 0; rr < 2; ++rr) {
        int bb = bg + 8 * rr;
        float ar = 0.f, ai = 0.f;
#pragma unroll
        for (int ii = 0; ii < 32; ++ii) {
            float2 xv = xbl[bb * 32 + ii];
            float wr_ = wrl[ii * 32 + o], wi_ = wil[ii * 32 + o];
            ar = fmaf(xv.x, wr_, ar); ar = fmaf(-xv.y, wi_, ar);
            ai = fmaf(xv.x, wi_, ai); ai = fmaf(xv.y, wr_, ai);
        }
        oft[(size_t)bb * 17408 + (size_t)m * 544 + (size_t)kw * 32 + o] =
            make_float2(ar, ai);
    }
}

// ---------------- K4: inverse H-DFT (32 modes -> 256 y) ----------------
// grid = 16*17*2 = 544 blocks: (b, kw, o-half); thread = y. T: [b][y][kw][o] f2
__global__ __launch_bounds__(256) void k4_invH(const float2* __restrict__ oft,
                                               float2* __restrict__ T) {
    __shared__ __align__(16) float2 ol[32 * 16];      // [m][o-half], 4 KB
    const int t = threadIdx.x;
    const int bk = blockIdx.x;
    const int b = bk / 34;
    const int rem = bk - b * 34;
    const int kw = rem >> 1, oh = rem & 1;
    {
        int mm = t >> 3, quad = t & 7;       // 256 f4 = 512 f2
        ((float4*)ol)[t] = *(const float4*)(oft + (size_t)b * 17408 +
                                            (size_t)mm * 544 + (size_t)kw * 32 + oh * 16 + quad * 2);
    }
    __syncthreads();
    const int y = t;
    float uc, us; sincosf(TWO_PI * (float)y * (1.f / 256.f), &us, &uc);
    float tr = 1.f, ti = 0.f;
    float ar[16], ai[16];
    #pragma unroll
    for (int o = 0; o < 16; ++o) { ar[o] = 0.f; ai[o] = 0.f; }
    for (int m = 0; m < 32; ++m) {
        if (m == 16) ti = -ti;               // kh jumps +16 -> -16
        #pragma unroll
        for (int o2 = 0; o2 < 8; ++o2) {
            float4 v = *(const float4*)((const float*)ol + m * 32 + o2 * 4);
            int o = o2 * 2;
            ar[o]   = fmaf(v.x, tr, ar[o]);   ar[o]   = fmaf(-v.y, ti, ar[o]);
            ai[o]   = fmaf(v.x, ti, ai[o]);   ai[o]   = fmaf(v.y, tr, ai[o]);
            ar[o+1] = fmaf(v.z, tr, ar[o+1]); ar[o+1] = fmaf(-v.w, ti, ar[o+1]);
            ai[o+1] = fmaf(v.z, ti, ai[o+1]); ai[o+1] = fmaf(v.w, tr, ai[o+1]);
        }
        cmul_upd(tr, ti, uc, us);
    }
    float2* dst = T + ((size_t)(b * 256 + y) * 17 + kw) * 32 + oh * 16;
    #pragma unroll
    for (int o2 = 0; o2 < 8; ++o2) {
        *(float4*)(dst + o2 * 2) =
            make_float4(ar[o2*2], ai[o2*2], ar[o2*2+1], ai[o2*2+1]);
    }
}

// ---------------- K5: inverse W reconstruction + bias ----------------
// grid = 4096 blocks (one per (b,y)); lane = (x-quad, o-oct)
__global__ __launch_bounds__(256) void k5_invW(const float2* __restrict__ T,
                                               const float* __restrict__ bias,
                                               float* __restrict__ out) {
    __shared__ __align__(16) float2 tl[544];          // [kw][o]
    __shared__ float bl[32];
    const int t = threadIdx.x;
    const int blk = blockIdx.x;                       // b*256 + y
    const float4* src4 = (const float4*)(T + (size_t)blk * 544);
    for (int u = t; u < 272; u += 256) ((float4*)tl)[u] = src4[u];
    if (t < 32) bl[t] = bias[t];
    __syncthreads();
    const int o8 = t & 3, xq = t >> 2;                // o base = o8*8, x = xq*4 + k
    float c0, s0; sincosf(TWO_PI * (float)(xq * 4) * (1.f / 256.f), &s0, &c0);
    const float CC = 0.99969881869620422f, SS = 0.02454122852291229f;  // e^{2pi i/256}
    float ur[4], ui[4];
    ur[0] = c0; ui[0] = s0;
    #pragma unroll
    for (int k = 1; k < 4; ++k) {
        ur[k] = ur[k-1] * CC - ui[k-1] * SS;
        ui[k] = ur[k-1] * SS + ui[k-1] * CC;
    }
    float tr_[4], ti_[4];
    #pragma unroll
    for (int k = 0; k < 4; ++k) { tr_[k] = ur[k]; ti_[k] = ui[k]; }
    float acc[4][8];
    #pragma unroll
    for (int k = 0; k < 4; ++k)
        #pragma unroll
        for (int o = 0; o < 8; ++o) acc[k][o] = 0.f;
    #pragma unroll 4
    for (int kw = 1; kw < 17; ++kw) {
        #pragma unroll
        for (int o2 = 0; o2 < 4; ++o2) {
            float4 v = *(const float4*)((const float*)tl + kw * 64 + o8 * 16 + o2 * 4);
            #pragma unroll
            for (int k = 0; k < 4; ++k) {
                acc[k][o2*2]   = fmaf(v.x, tr_[k], acc[k][o2*2]);
                acc[k][o2*2]   = fmaf(-v.y, ti_[k], acc[k][o2*2]);
                acc[k][o2*2+1] = fmaf(v.z, tr_[k], acc[k][o2*2+1]);
                acc[k][o2*2+1] = fmaf(-v.w, ti_[k], acc[k][o2*2+1]);
            }
        }
        #pragma unroll
        for (int k = 0; k < 4; ++k) cmul_upd(tr_[k], ti_[k], ur[k], ui[k]);
    }
    float base[8];
    #pragma unroll
    for (int o = 0; o < 8; ++o) {
        int og = o8 * 8 + o;
        base[o] = tl[og].x + bl[og];                  // Re(T0) + bias
    }
    float* orow = out + (size_t)blk * 8192;
    #pragma unroll
    for (int k = 0; k < 4; ++k) {
        int xx = xq * 4 + k;
        float res[8];
        #pragma unroll
        for (int o = 0; o < 8; ++o) res[o] = fmaf(2.f, acc[k][o], base[o]);
        float* dst = orow + xx * 32 + o8 * 8;
        *(float4*)(dst)     = make_float4(res[0], res[1], res[2], res[3]);
        *(float4*)(dst + 4) = make_float4(res[4], res[5], res[6], res[7]);
    }
}

extern "C" void kernel_launch(void* const* d_in, const int* in_sizes, int n_in,
                              void* d_out, int out_size, void* d_ws, size_t ws_size,
                              hipStream_t stream) {
    const float* x    = (const float*)d_in[0];
    const float* w1r  = (const float*)d_in[1];
    const float* w1i  = (const float*)d_in[2];
    const float* w2r  = (const float*)d_in[3];
    const float* w2i  = (const float*)d_in[4];
    const float* bias = (const float*)d_in[5];
    float* out = (float*)d_out;

    char* ws = (char*)d_ws;
    // Xw: 16*17*256*32 f2 = 17,825,792 B  (aliased with T: Xw dead after K2)
    float2* Xw  = (float2*)ws;
    float2* T   = Xw;
    float2* xft = (float2*)(ws + 17825792);               // 2,228,224 B
    float2* oft = (float2*)(ws + 17825792 + 2228224);     // 2,228,224 B

    k1_fwdW_mfma<<<512, 256, 0, stream>>>(x, (float*)Xw);
    k2_fwdH<<<NB * EM1 * 2, 256, 0, stream>>>(Xw, xft);
    k3_mix <<<32 * EM1, 256, 0, stream>>>(xft, w1r, w1i, w2r, w2i, oft);
    k4_invH<<<NB * EM1 * 2, 256, 0, stream>>>(oft, T);
    k5_invW<<<NB * NH, 256, 0, stream>>>(T, bias, out);
}